// Round 1
// baseline (95.712 us; speedup 1.0000x reference)
//
#include <hip/hip_runtime.h>
#include <hip/hip_bf16.h>

typedef __attribute__((ext_vector_type(8))) short bf16x8;
typedef __attribute__((ext_vector_type(4))) float f32x4;

#define BDIM 4096
#define HDIM 1024
#define KDIM 2048

#define BM 128
#define BN 64
#define BK 64
#define NKT (KDIM / BK)

__device__ __forceinline__ unsigned short f2bf(float f) {
  union { float fv; unsigned int u; } c; c.fv = f;
  unsigned int u = c.u;
  unsigned int r = (u + 0x7FFFu + ((u >> 16) & 1u)) >> 16;
  return (unsigned short)r;
}

__device__ __forceinline__ void gload_lds16(const unsigned short* g, unsigned short* l) {
  auto gp = reinterpret_cast<const __attribute__((address_space(1))) unsigned int*>(
      reinterpret_cast<uintptr_t>(g));
  auto lp = reinterpret_cast<__attribute__((address_space(3))) unsigned int*>(
      reinterpret_cast<uintptr_t>(l));
  __builtin_amdgcn_global_load_lds(gp, lp, 16, 0, 0);
}

__device__ __forceinline__ float sigm(float z) {
  return 1.0f / (1.0f + __expf(-z));
}
__device__ __forceinline__ float tanh_fast(float z) {
  return 1.0f - 2.0f / (__expf(2.0f * z) + 1.0f);
}

// Build hx = [x | h] as bf16 [4096][2048]
__global__ void pack_hx_kernel(const float* __restrict__ x, const float* __restrict__ h,
                               unsigned short* __restrict__ hx) {
  int idx = (blockIdx.x * blockDim.x + threadIdx.x) * 4;
  int row = idx >> 11;
  int col = idx & 2047;
  const float* src = (col < 1024) ? (x + (size_t)row * 1024 + col)
                                  : (h + (size_t)row * 1024 + (col - 1024));
  float4 v = *reinterpret_cast<const float4*>(src);
  ushort4 o = make_ushort4(f2bf(v.x), f2bf(v.y), f2bf(v.z), f2bf(v.w));
  *reinterpret_cast<ushort4*>(hx + idx) = o;
}

// W [2048][1024] f32 -> Wt [1024][2048] bf16
__global__ void transpose_w_kernel(const float* __restrict__ W, unsigned short* __restrict__ Wt) {
  __shared__ float tile[32][33];
  int n0 = blockIdx.x * 32;
  int k0 = blockIdx.y * 32;
  int tx = threadIdx.x;
  int ty = threadIdx.y;
#pragma unroll
  for (int i = 0; i < 4; ++i)
    tile[ty + 8 * i][tx] = W[(size_t)(k0 + ty + 8 * i) * 1024 + (n0 + tx)];
  __syncthreads();
#pragma unroll
  for (int i = 0; i < 4; ++i)
    Wt[(size_t)(n0 + ty + 8 * i) * 2048 + (k0 + tx)] = f2bf(tile[tx][ty + 8 * i]);
}

// Fused 4-gate GEMM + LSTM epilogue.
// Grid: (4096/128)*(1024/64) = 512 blocks, 256 threads (4 waves, 2x2).
__global__ __launch_bounds__(256, 2) void lstm_fused_kernel(
    const unsigned short* __restrict__ hx,
    const unsigned short* __restrict__ wt0,
    const unsigned short* __restrict__ wt1,
    const unsigned short* __restrict__ wt2,
    const unsigned short* __restrict__ wt3,
    const float* __restrict__ bias_f,
    const float* __restrict__ bias_i,
    const float* __restrict__ bias_s,
    const float* __restrict__ bias_p,
    const float* __restrict__ c_in,
    float* __restrict__ out) {
  __shared__ unsigned short lA[BM * BK];      // 16 KB
  __shared__ unsigned short lB[4 * BN * BK];  // 32 KB

  const int tid  = threadIdx.x;
  const int lane = tid & 63;
  const int wid  = tid >> 6;
  const int wr   = wid >> 1;  // 0..1
  const int wc   = wid & 1;   // 0..1

  const int brow = blockIdx.x >> 4;  // 0..31
  const int bcol = blockIdx.x & 15;  // 0..15

  const unsigned short* wts[4] = {wt0, wt1, wt2, wt3};

  f32x4 acc[4][4][2];
#pragma unroll
  for (int g = 0; g < 4; ++g)
#pragma unroll
    for (int m = 0; m < 4; ++m)
#pragma unroll
      for (int n = 0; n < 2; ++n)
        acc[g][m][n] = (f32x4)(0.0f);

  for (int kt = 0; kt < NKT; ++kt) {
    const int kbase = kt * BK;
    // stage A tile: 128 rows x 64 k, swizzled source chunks, linear LDS
#pragma unroll
    for (int i = 0; i < 4; ++i) {
      int c = i * 256 + tid;
      int row = c >> 3, cc = c & 7;
      int scc = cc ^ (row & 7);
      gload_lds16(hx + (size_t)(brow * 128 + row) * KDIM + kbase + scc * 8,
                  lA + c * 8);
    }
    // stage 4 B tiles: each 64 rows (cols of W) x 64 k
#pragma unroll
    for (int i = 0; i < 8; ++i) {
      int c = i * 256 + tid;
      const int gate = i >> 1;  // compile-time per unrolled i
      int idx = c & 511;
      int row = idx >> 3, cc = idx & 7;
      int scc = cc ^ (row & 7);
      gload_lds16(wts[gate] + (size_t)(bcol * 64 + row) * KDIM + kbase + scc * 8,
                  lB + c * 8);
    }
    __syncthreads();  // drains vmcnt + barrier

    {
      const int lg = lane >> 4;  // 0..3
      const int ll = lane & 15;
      bf16x8 aF[4][2];
#pragma unroll
      for (int m = 0; m < 4; ++m) {
        int row = wr * 64 + m * 16 + ll;
#pragma unroll
        for (int ks = 0; ks < 2; ++ks) {
          int ch = (ks * 4 + lg) ^ (row & 7);
          aF[m][ks] = *reinterpret_cast<const bf16x8*>(lA + row * 64 + ch * 8);
        }
      }
#pragma unroll
      for (int g = 0; g < 4; ++g) {
        bf16x8 bF[2][2];
#pragma unroll
        for (int n = 0; n < 2; ++n) {
          int row = wc * 32 + n * 16 + ll;
#pragma unroll
          for (int ks = 0; ks < 2; ++ks) {
            int ch = (ks * 4 + lg) ^ (row & 7);
            bF[n][ks] = *reinterpret_cast<const bf16x8*>(lB + g * 4096 + row * 64 + ch * 8);
          }
        }
#pragma unroll
        for (int m = 0; m < 4; ++m)
#pragma unroll
          for (int n = 0; n < 2; ++n)
#pragma unroll
            for (int ks = 0; ks < 2; ++ks)
              acc[g][m][n] = __builtin_amdgcn_mfma_f32_16x16x32_bf16(
                  aF[m][ks], bF[n][ks], acc[g][m][n], 0, 0, 0);
      }
    }
    __syncthreads();  // all waves done reading before next overwrite
  }

  // epilogue: gates + cell update, store h_new
  const int lg = lane >> 4;
  const int ll = lane & 15;
  const int row0 = brow * 128 + wr * 64;
  const int col0 = bcol * 64 + wc * 32;
  float bv[4][2];
#pragma unroll
  for (int n = 0; n < 2; ++n) {
    int col = col0 + n * 16 + ll;
    bv[0][n] = bias_f[col];
    bv[1][n] = bias_i[col];
    bv[2][n] = bias_s[col];
    bv[3][n] = bias_p[col];
  }
#pragma unroll
  for (int m = 0; m < 4; ++m)
#pragma unroll
    for (int n = 0; n < 2; ++n)
#pragma unroll
      for (int j = 0; j < 4; ++j) {
        int row = row0 + m * 16 + lg * 4 + j;
        int col = col0 + n * 16 + ll;
        float zf = acc[0][m][n][j] + bv[0][n];
        float zi = acc[1][m][n][j] + bv[1][n];
        float zs = acc[2][m][n][j] + bv[2][n];
        float zp = acc[3][m][n][j] + bv[3][n];
        float fg = sigm(zf);
        float ig = sigm(zi);
        float sg = sigm(zs);
        float pg = tanh_fast(zp);
        float cn = c_in[(size_t)row * 1024 + col] * fg + ig * pg;
        out[(size_t)row * 1024 + col] = tanh_fast(cn) * sg;
      }
}

extern "C" void kernel_launch(void* const* d_in, const int* in_sizes, int n_in,
                              void* d_out, int out_size, void* d_ws, size_t ws_size,
                              hipStream_t stream) {
  const float* x  = (const float*)d_in[0];
  const float* h  = (const float*)d_in[1];
  const float* c  = (const float*)d_in[2];
  const float* Wf = (const float*)d_in[3];
  const float* bf = (const float*)d_in[4];
  const float* Wi = (const float*)d_in[5];
  const float* bi = (const float*)d_in[6];
  const float* Ws = (const float*)d_in[7];
  const float* bs = (const float*)d_in[8];
  const float* Wp = (const float*)d_in[9];
  const float* bp = (const float*)d_in[10];
  float* out = (float*)d_out;

  unsigned short* ws = (unsigned short*)d_ws;
  unsigned short* hx = ws;  // 4096*2048 bf16 = 16 MB
  unsigned short* wt[4];
  for (int g = 0; g < 4; ++g)
    wt[g] = ws + (size_t)4096 * 2048 + (size_t)g * 1024 * 2048;  // 4 MB each

  pack_hx_kernel<<<(BDIM * KDIM / 4) / 256, 256, 0, stream>>>(x, h, hx);

  dim3 tb(32, 8);
  dim3 tg(1024 / 32, 2048 / 32);
  transpose_w_kernel<<<tg, tb, 0, stream>>>(Wf, wt[0]);
  transpose_w_kernel<<<tg, tb, 0, stream>>>(Wi, wt[1]);
  transpose_w_kernel<<<tg, tb, 0, stream>>>(Ws, wt[2]);
  transpose_w_kernel<<<tg, tb, 0, stream>>>(Wp, wt[3]);

  lstm_fused_kernel<<<512, 256, 0, stream>>>(hx, wt[0], wt[1], wt[2], wt[3],
                                             bf, bi, bs, bp, c, out);
}

// Round 2
// 88.008 us; speedup vs baseline: 1.0875x; 1.0875x over previous
//
#include <hip/hip_runtime.h>
#include <hip/hip_bf16.h>

typedef __attribute__((ext_vector_type(8))) short bf16x8;
typedef __attribute__((ext_vector_type(4))) float f32x4;

#define BDIM 4096
#define HDIM 1024
#define KDIM 2048

#define BM 256
#define BN 64
#define BK 64
#define NKT (KDIM / BK)

__device__ __forceinline__ unsigned short f2bf(float f) {
  union { float fv; unsigned int u; } c; c.fv = f;
  unsigned int u = c.u;
  unsigned int r = (u + 0x7FFFu + ((u >> 16) & 1u)) >> 16;
  return (unsigned short)r;
}

__device__ __forceinline__ void gload_lds16(const unsigned short* g, unsigned short* l) {
  auto gp = reinterpret_cast<const __attribute__((address_space(1))) unsigned int*>(
      reinterpret_cast<uintptr_t>(g));
  auto lp = reinterpret_cast<__attribute__((address_space(3))) unsigned int*>(
      reinterpret_cast<uintptr_t>(l));
  __builtin_amdgcn_global_load_lds(gp, lp, 16, 0, 0);
}

__device__ __forceinline__ float sigm(float z) {
  return 1.0f / (1.0f + __expf(-z));
}
__device__ __forceinline__ float tanh_fast(float z) {
  return 1.0f - 2.0f / (__expf(2.0f * z) + 1.0f);
}

// Build hx = [x | h] as bf16 [4096][2048]
__global__ void pack_hx_kernel(const float* __restrict__ x, const float* __restrict__ h,
                               unsigned short* __restrict__ hx) {
  int idx = (blockIdx.x * blockDim.x + threadIdx.x) * 4;
  int row = idx >> 11;
  int col = idx & 2047;
  const float* src = (col < 1024) ? (x + (size_t)row * 1024 + col)
                                  : (h + (size_t)row * 1024 + (col - 1024));
  float4 v = *reinterpret_cast<const float4*>(src);
  ushort4 o = make_ushort4(f2bf(v.x), f2bf(v.y), f2bf(v.z), f2bf(v.w));
  *reinterpret_cast<ushort4*>(hx + idx) = o;
}

// All four W [2048][1024] f32 -> Wt [4][1024][2048] bf16 in one launch (z = gate)
__global__ void transpose_w4_kernel(const float* __restrict__ W0, const float* __restrict__ W1,
                                    const float* __restrict__ W2, const float* __restrict__ W3,
                                    unsigned short* __restrict__ Wt) {
  __shared__ float tile[32][33];
  const int g = blockIdx.z;
  const float* W = (g == 0) ? W0 : (g == 1) ? W1 : (g == 2) ? W2 : W3;
  unsigned short* T = Wt + (size_t)g * 1024 * 2048;
  int n0 = blockIdx.x * 32;
  int k0 = blockIdx.y * 32;
  int tx = threadIdx.x;
  int ty = threadIdx.y;
#pragma unroll
  for (int i = 0; i < 4; ++i)
    tile[ty + 8 * i][tx] = W[(size_t)(k0 + ty + 8 * i) * 1024 + (n0 + tx)];
  __syncthreads();
#pragma unroll
  for (int i = 0; i < 4; ++i)
    T[(size_t)(n0 + ty + 8 * i) * 2048 + (k0 + tx)] = f2bf(tile[tx][ty + 8 * i]);
}

#define MFMA_GATE(G)                                                            \
  {                                                                             \
    _Pragma("unroll") for (int m = 0; m < 4; ++m)                               \
        _Pragma("unroll") for (int n = 0; n < 2; ++n)                           \
            _Pragma("unroll") for (int ks = 0; ks < 2; ++ks)                    \
                acc[G][m][n] = __builtin_amdgcn_mfma_f32_16x16x32_bf16(         \
                    aF[m][ks], bF[n][ks], acc[G][m][n], 0, 0, 0);               \
  }

// Fused 4-gate GEMM + LSTM epilogue, 8-phase-style schedule (4 phases/K-step).
// Grid: (4096/256)*(1024/64) = 256 blocks, 512 threads (8 waves, 4x2).
__global__ __launch_bounds__(512, 2) void lstm_fused_kernel(
    const unsigned short* __restrict__ hx,
    const unsigned short* __restrict__ wtb,
    const float* __restrict__ bias_f,
    const float* __restrict__ bias_i,
    const float* __restrict__ bias_s,
    const float* __restrict__ bias_p,
    const float* __restrict__ c_in,
    float* __restrict__ out) {
  __shared__ unsigned short lA[2][BM * BK];      // 2 x 32 KB
  __shared__ unsigned short lB[2][4 * BN * BK];  // 2 x 32 KB

  const int tid  = threadIdx.x;
  const int lane = tid & 63;
  const int wid  = tid >> 6;
  const int wr   = wid >> 1;  // 0..3 : 64-row slice
  const int wc   = wid & 1;   // 0..1 : 32-col slice
  const int lg   = lane >> 4;
  const int ll   = lane & 15;

  // bijective XCD swizzle (256 blocks, 256 % 8 == 0)
  const int wg   = (blockIdx.x & 7) * 32 + (blockIdx.x >> 3);
  const int brow = wg >> 4;  // 0..15
  const int bcol = wg & 15;  // 0..15

  const unsigned short* wts[4];
#pragma unroll
  for (int g = 0; g < 4; ++g) wts[g] = wtb + (size_t)g * 1024 * 2048;

  // ---- staging descriptors (per-thread, hoisted) ----
  const unsigned short* srcA[4];
  unsigned int dA[4];
#pragma unroll
  for (int i = 0; i < 4; ++i) {
    int s = i * 512 + tid;       // slot 0..2047
    int r = s >> 3, sch = s & 7;
    int ch = sch ^ (r & 7);      // inverse swizzle on global source
    srcA[i] = hx + (size_t)(brow * 256 + r) * KDIM + ch * 8;
    dA[i] = s * 8;
  }
  const unsigned short* srcB[4];
  unsigned int dB[4];
  {
    int r = tid >> 3, sch = tid & 7;
    int ch = sch ^ (r & 7);
#pragma unroll
    for (int g = 0; g < 4; ++g) {
      srcB[g] = wts[g] + (size_t)(bcol * 64 + r) * KDIM + ch * 8;
      dB[g] = g * 4096 + tid * 8;
    }
  }

  // ---- fragment LDS offsets (element offsets within a buffer) ----
  unsigned int aoff[4][2], boff[2][2];
#pragma unroll
  for (int m = 0; m < 4; ++m) {
    int row = wr * 64 + m * 16 + ll;
#pragma unroll
    for (int ks = 0; ks < 2; ++ks) {
      int ch = (ks * 4 + lg) ^ (row & 7);
      aoff[m][ks] = row * 64 + ch * 8;
    }
  }
#pragma unroll
  for (int n = 0; n < 2; ++n) {
    int row = wc * 32 + n * 16 + ll;
#pragma unroll
    for (int ks = 0; ks < 2; ++ks) {
      int ch = (ks * 4 + lg) ^ (row & 7);
      boff[n][ks] = row * 64 + ch * 8;
    }
  }

  f32x4 acc[4][4][2];
#pragma unroll
  for (int g = 0; g < 4; ++g)
#pragma unroll
    for (int m = 0; m < 4; ++m)
#pragma unroll
      for (int n = 0; n < 2; ++n)
        acc[g][m][n] = (f32x4)(0.0f);

  // ---- prologue: stage K-tile 0 into buffer 0 ----
#pragma unroll
  for (int i = 0; i < 4; ++i) gload_lds16(srcA[i], &lA[0][dA[i]]);
#pragma unroll
  for (int g = 0; g < 4; ++g) gload_lds16(srcB[g], &lB[0][dB[g]]);
#pragma unroll
  for (int i = 0; i < 4; ++i) srcA[i] += BK;
#pragma unroll
  for (int g = 0; g < 4; ++g) srcB[g] += BK;
  asm volatile("s_waitcnt vmcnt(0)" ::: "memory");
  __builtin_amdgcn_sched_barrier(0);
  __builtin_amdgcn_s_barrier();

  for (int kt = 0; kt < NKT; ++kt) {
    const int p = kt & 1;
    const unsigned short* Ab = &lA[p][0];
    const unsigned short* Bb = &lB[p][0];
    unsigned short* An = &lA[p ^ 1][0];
    unsigned short* Bn = &lB[p ^ 1][0];
    const bool has_next = (kt < NKT - 1);

    bf16x8 aF[4][2];
    bf16x8 bF[2][2];

    // ---------- phase 0 (gate 0): read aF + bF0, stage next A ----------
#pragma unroll
    for (int m = 0; m < 4; ++m)
#pragma unroll
      for (int ks = 0; ks < 2; ++ks)
        aF[m][ks] = *reinterpret_cast<const bf16x8*>(Ab + aoff[m][ks]);
#pragma unroll
    for (int n = 0; n < 2; ++n)
#pragma unroll
      for (int ks = 0; ks < 2; ++ks)
        bF[n][ks] = *reinterpret_cast<const bf16x8*>(Bb + boff[n][ks]);
    if (has_next) {
#pragma unroll
      for (int i = 0; i < 4; ++i) gload_lds16(srcA[i], An + dA[i]);
    }
    __builtin_amdgcn_s_barrier();
    asm volatile("s_waitcnt lgkmcnt(0)" ::: "memory");
    __builtin_amdgcn_sched_barrier(0);
    __builtin_amdgcn_s_setprio(1);
    MFMA_GATE(0)
    __builtin_amdgcn_s_setprio(0);
    __builtin_amdgcn_s_barrier();

    // ---------- phase 1 (gate 1): read bF1, stage next B ----------
#pragma unroll
    for (int n = 0; n < 2; ++n)
#pragma unroll
      for (int ks = 0; ks < 2; ++ks)
        bF[n][ks] = *reinterpret_cast<const bf16x8*>(Bb + 4096 + boff[n][ks]);
    if (has_next) {
#pragma unroll
      for (int g = 0; g < 4; ++g) gload_lds16(srcB[g], Bn + dB[g]);
    }
    __builtin_amdgcn_s_barrier();
    asm volatile("s_waitcnt lgkmcnt(0)" ::: "memory");
    __builtin_amdgcn_sched_barrier(0);
    __builtin_amdgcn_s_setprio(1);
    MFMA_GATE(1)
    __builtin_amdgcn_s_setprio(0);
    __builtin_amdgcn_s_barrier();

    // ---------- phase 2 (gate 2): read bF2 ----------
#pragma unroll
    for (int n = 0; n < 2; ++n)
#pragma unroll
      for (int ks = 0; ks < 2; ++ks)
        bF[n][ks] = *reinterpret_cast<const bf16x8*>(Bb + 2 * 4096 + boff[n][ks]);
    __builtin_amdgcn_s_barrier();
    asm volatile("s_waitcnt lgkmcnt(0)" ::: "memory");
    __builtin_amdgcn_sched_barrier(0);
    __builtin_amdgcn_s_setprio(1);
    MFMA_GATE(2)
    __builtin_amdgcn_s_setprio(0);
    __builtin_amdgcn_s_barrier();

    // ---------- phase 3 (gate 3): read bF3, drain staging, flip ----------
#pragma unroll
    for (int n = 0; n < 2; ++n)
#pragma unroll
      for (int ks = 0; ks < 2; ++ks)
        bF[n][ks] = *reinterpret_cast<const bf16x8*>(Bb + 3 * 4096 + boff[n][ks]);
    __builtin_amdgcn_s_barrier();
    asm volatile("s_waitcnt lgkmcnt(0)" ::: "memory");
    __builtin_amdgcn_sched_barrier(0);
    __builtin_amdgcn_s_setprio(1);
    MFMA_GATE(3)
    __builtin_amdgcn_s_setprio(0);
    asm volatile("s_waitcnt vmcnt(0)" ::: "memory");
    __builtin_amdgcn_sched_barrier(0);
    __builtin_amdgcn_s_barrier();

#pragma unroll
    for (int i = 0; i < 4; ++i) srcA[i] += BK;
#pragma unroll
    for (int g = 0; g < 4; ++g) srcB[g] += BK;
  }

  // ---- epilogue: gates + cell update, store h_new ----
  const int row0 = brow * 256 + wr * 64;
  const int col0 = bcol * 64 + wc * 32;
  float bv[4][2];
#pragma unroll
  for (int n = 0; n < 2; ++n) {
    int col = col0 + n * 16 + ll;
    bv[0][n] = bias_f[col];
    bv[1][n] = bias_i[col];
    bv[2][n] = bias_s[col];
    bv[3][n] = bias_p[col];
  }
#pragma unroll
  for (int m = 0; m < 4; ++m)
#pragma unroll
    for (int n = 0; n < 2; ++n)
#pragma unroll
      for (int j = 0; j < 4; ++j) {
        int row = row0 + m * 16 + lg * 4 + j;
        int col = col0 + n * 16 + ll;
        float zf = acc[0][m][n][j] + bv[0][n];
        float zi = acc[1][m][n][j] + bv[1][n];
        float zs = acc[2][m][n][j] + bv[2][n];
        float zp = acc[3][m][n][j] + bv[3][n];
        float fg = sigm(zf);
        float ig = sigm(zi);
        float sg = sigm(zs);
        float pg = tanh_fast(zp);
        float cn = c_in[(size_t)row * 1024 + col] * fg + ig * pg;
        out[(size_t)row * 1024 + col] = tanh_fast(cn) * sg;
      }
}

extern "C" void kernel_launch(void* const* d_in, const int* in_sizes, int n_in,
                              void* d_out, int out_size, void* d_ws, size_t ws_size,
                              hipStream_t stream) {
  const float* x  = (const float*)d_in[0];
  const float* h  = (const float*)d_in[1];
  const float* c  = (const float*)d_in[2];
  const float* Wf = (const float*)d_in[3];
  const float* bf = (const float*)d_in[4];
  const float* Wi = (const float*)d_in[5];
  const float* bi = (const float*)d_in[6];
  const float* Ws = (const float*)d_in[7];
  const float* bs = (const float*)d_in[8];
  const float* Wp = (const float*)d_in[9];
  const float* bp = (const float*)d_in[10];
  float* out = (float*)d_out;

  unsigned short* ws = (unsigned short*)d_ws;
  unsigned short* hx  = ws;                           // 4096*2048 bf16 = 16 MB
  unsigned short* wtb = ws + (size_t)4096 * 2048;     // 4*1024*2048 bf16 = 16 MB

  pack_hx_kernel<<<(BDIM * KDIM / 4) / 256, 256, 0, stream>>>(x, h, hx);

  dim3 tb(32, 8);
  dim3 tg(1024 / 32, 2048 / 32, 4);
  transpose_w4_kernel<<<tg, tb, 0, stream>>>(Wf, Wi, Ws, Wp, wtb);

  lstm_fused_kernel<<<256, 512, 0, stream>>>(hx, wtb, bf, bi, bs, bp, c, out);
}

// Round 3
// 87.564 us; speedup vs baseline: 1.0931x; 1.0051x over previous
//
#include <hip/hip_runtime.h>
#include <hip/hip_bf16.h>

typedef __attribute__((ext_vector_type(8))) short bf16x8;
typedef __attribute__((ext_vector_type(4))) float f32x4;

#define BDIM 4096
#define HDIM 1024
#define KDIM 2048

#define BM 256
#define BN 64
#define BK 64
#define NKT (KDIM / BK)

__device__ __forceinline__ unsigned short f2bf(float f) {
  union { float fv; unsigned int u; } c; c.fv = f;
  unsigned int u = c.u;
  unsigned int r = (u + 0x7FFFu + ((u >> 16) & 1u)) >> 16;
  return (unsigned short)r;
}

__device__ __forceinline__ void gload_lds16(const unsigned short* g, unsigned short* l) {
  auto gp = reinterpret_cast<const __attribute__((address_space(1))) unsigned int*>(
      reinterpret_cast<uintptr_t>(g));
  auto lp = reinterpret_cast<__attribute__((address_space(3))) unsigned int*>(
      reinterpret_cast<uintptr_t>(l));
  __builtin_amdgcn_global_load_lds(gp, lp, 16, 0, 0);
}

__device__ __forceinline__ float sigm(float z) {
  return 1.0f / (1.0f + __expf(-z));
}
__device__ __forceinline__ float tanh_fast(float z) {
  return 1.0f - 2.0f / (__expf(2.0f * z) + 1.0f);
}

// Build hx = [x | h] as bf16 [4096][2048]
__global__ void pack_hx_kernel(const float* __restrict__ x, const float* __restrict__ h,
                               unsigned short* __restrict__ hx) {
  int idx = (blockIdx.x * blockDim.x + threadIdx.x) * 4;
  int row = idx >> 11;
  int col = idx & 2047;
  const float* src = (col < 1024) ? (x + (size_t)row * 1024 + col)
                                  : (h + (size_t)row * 1024 + (col - 1024));
  float4 v = *reinterpret_cast<const float4*>(src);
  ushort4 o = make_ushort4(f2bf(v.x), f2bf(v.y), f2bf(v.z), f2bf(v.w));
  *reinterpret_cast<ushort4*>(hx + idx) = o;
}

// All four W [2048][1024] f32 -> Wt [4][1024][2048] bf16 in one launch (z = gate)
__global__ void transpose_w4_kernel(const float* __restrict__ W0, const float* __restrict__ W1,
                                    const float* __restrict__ W2, const float* __restrict__ W3,
                                    unsigned short* __restrict__ Wt) {
  __shared__ float tile[32][33];
  const int g = blockIdx.z;
  const float* W = (g == 0) ? W0 : (g == 1) ? W1 : (g == 2) ? W2 : W3;
  unsigned short* T = Wt + (size_t)g * 1024 * 2048;
  int n0 = blockIdx.x * 32;
  int k0 = blockIdx.y * 32;
  int tx = threadIdx.x;
  int ty = threadIdx.y;
#pragma unroll
  for (int i = 0; i < 4; ++i)
    tile[ty + 8 * i][tx] = W[(size_t)(k0 + ty + 8 * i) * 1024 + (n0 + tx)];
  __syncthreads();
#pragma unroll
  for (int i = 0; i < 4; ++i)
    T[(size_t)(n0 + ty + 8 * i) * 2048 + (k0 + tx)] = f2bf(tile[tx][ty + 8 * i]);
}

#define MFMA_GATE(G)                                                            \
  {                                                                             \
    _Pragma("unroll") for (int m = 0; m < 4; ++m)                               \
        _Pragma("unroll") for (int n = 0; n < 2; ++n)                           \
            _Pragma("unroll") for (int ks = 0; ks < 2; ++ks)                    \
                acc[G][m][n] = __builtin_amdgcn_mfma_f32_16x16x32_bf16(         \
                    aF[m][ks], bF[n][ks], acc[G][m][n], 0, 0, 0);               \
  }

#define READ_BF(G)                                                              \
  {                                                                             \
    _Pragma("unroll") for (int n = 0; n < 2; ++n)                               \
        _Pragma("unroll") for (int ks = 0; ks < 2; ++ks)                        \
            bF[n][ks] = *reinterpret_cast<const bf16x8*>(Bb + (G)*4096 + boff[n][ks]); \
  }

#define READ_AF()                                                               \
  {                                                                             \
    _Pragma("unroll") for (int m = 0; m < 4; ++m)                               \
        _Pragma("unroll") for (int ks = 0; ks < 2; ++ks)                        \
            aF[m][ks] = *reinterpret_cast<const bf16x8*>(Ab + aoff[m][ks]);     \
  }

#define PHASE_MID()                                                             \
  __builtin_amdgcn_s_barrier();                                                 \
  asm volatile("s_waitcnt lgkmcnt(0)" ::: "memory");                            \
  __builtin_amdgcn_sched_barrier(0);                                            \
  __builtin_amdgcn_s_setprio(1);

#define PHASE_END(VMSTR)                                                        \
  __builtin_amdgcn_s_setprio(0);                                                \
  asm volatile("s_waitcnt " VMSTR ::: "memory");                                \
  __builtin_amdgcn_sched_barrier(0);                                            \
  __builtin_amdgcn_s_barrier();

// Fused 4-gate GEMM + LSTM epilogue, 4 phases/K-step with counted vmcnt (T3+T4+T5).
// Grid: (4096/256)*(1024/64) = 256 blocks, 512 threads (8 waves, 4x2).
__global__ __launch_bounds__(512, 2) void lstm_fused_kernel(
    const unsigned short* __restrict__ hx,
    const unsigned short* __restrict__ wtb,
    const float* __restrict__ bias_f,
    const float* __restrict__ bias_i,
    const float* __restrict__ bias_s,
    const float* __restrict__ bias_p,
    const float* __restrict__ c_in,
    float* __restrict__ out) {
  __shared__ unsigned short lA[2][BM * BK];      // 2 x 32 KB
  __shared__ unsigned short lB[2][4 * BN * BK];  // 2 x 32 KB

  const int tid  = threadIdx.x;
  const int lane = tid & 63;
  const int wid  = tid >> 6;
  const int wr   = wid >> 1;  // 0..3 : 64-row slice
  const int wc   = wid & 1;   // 0..1 : 32-col slice
  const int lg   = lane >> 4;
  const int ll   = lane & 15;

  // bijective XCD swizzle (256 blocks, 256 % 8 == 0)
  const int wg   = (blockIdx.x & 7) * 32 + (blockIdx.x >> 3);
  const int brow = wg >> 4;  // 0..15
  const int bcol = wg & 15;  // 0..15

  // ---- staging descriptors (per-thread, hoisted) ----
  const unsigned short* srcA[4];
  unsigned int dA[4];
#pragma unroll
  for (int i = 0; i < 4; ++i) {
    int s = i * 512 + tid;       // slot 0..2047
    int r = s >> 3, sch = s & 7;
    int ch = sch ^ (r & 7);      // inverse swizzle on global source
    srcA[i] = hx + (size_t)(brow * 256 + r) * KDIM + ch * 8;
    dA[i] = s * 8;
  }
  const unsigned short* srcB[4];
  unsigned int dB[4];
  {
    int r = tid >> 3, sch = tid & 7;
    int ch = sch ^ (r & 7);
#pragma unroll
    for (int g = 0; g < 4; ++g) {
      srcB[g] = wtb + (size_t)g * 1024 * 2048 + (size_t)(bcol * 64 + r) * KDIM + ch * 8;
      dB[g] = g * 4096 + tid * 8;
    }
  }

  // ---- fragment LDS offsets (element offsets within a buffer) ----
  unsigned int aoff[4][2], boff[2][2];
#pragma unroll
  for (int m = 0; m < 4; ++m) {
    int row = wr * 64 + m * 16 + ll;
#pragma unroll
    for (int ks = 0; ks < 2; ++ks) {
      int ch = (ks * 4 + lg) ^ (row & 7);
      aoff[m][ks] = row * 64 + ch * 8;
    }
  }
#pragma unroll
  for (int n = 0; n < 2; ++n) {
    int row = wc * 32 + n * 16 + ll;
#pragma unroll
    for (int ks = 0; ks < 2; ++ks) {
      int ch = (ks * 4 + lg) ^ (row & 7);
      boff[n][ks] = row * 64 + ch * 8;
    }
  }

  f32x4 acc[4][4][2];
#pragma unroll
  for (int g = 0; g < 4; ++g)
#pragma unroll
    for (int m = 0; m < 4; ++m)
#pragma unroll
      for (int n = 0; n < 2; ++n)
        acc[g][m][n] = (f32x4)(0.0f);

  // ---- prologue: stage K-tile 0 into buffer 0, full drain once ----
#pragma unroll
  for (int i = 0; i < 4; ++i) gload_lds16(srcA[i], &lA[0][dA[i]]);
#pragma unroll
  for (int g = 0; g < 4; ++g) gload_lds16(srcB[g], &lB[0][dB[g]]);
#pragma unroll
  for (int i = 0; i < 4; ++i) srcA[i] += BK;
#pragma unroll
  for (int g = 0; g < 4; ++g) srcB[g] += BK;
  asm volatile("s_waitcnt vmcnt(0)" ::: "memory");
  __builtin_amdgcn_sched_barrier(0);
  __builtin_amdgcn_s_barrier();

  // ---- main loop: tiles 0 .. NKT-2, counted vmcnt, never 0 ----
  for (int kt = 0; kt < NKT - 1; ++kt) {
    const int p = kt & 1;
    const unsigned short* Ab = &lA[p][0];
    const unsigned short* Bb = &lB[p][0];
    unsigned short* An = &lA[p ^ 1][0];
    unsigned short* Bn = &lB[p ^ 1][0];

    bf16x8 aF[4][2];
    bf16x8 bF[2][2];

    // phase 0 (gate 0): read aF+bF0; issue A(t+1)x4
    READ_AF()
    READ_BF(0)
#pragma unroll
    for (int i = 0; i < 4; ++i) gload_lds16(srcA[i], An + dA[i]);
    PHASE_MID()
    MFMA_GATE(0)
    PHASE_END("vmcnt(6)")   // retire B1(t)

    // phase 1 (gate 1): read bF1; issue B0,B1(t+1)
    READ_BF(1)
    gload_lds16(srcB[0], Bn + dB[0]);
    gload_lds16(srcB[1], Bn + dB[1]);
    PHASE_MID()
    MFMA_GATE(1)
    PHASE_END("vmcnt(7)")   // retire B2(t)

    // phase 2 (gate 2): read bF2; issue B2(t+1)
    READ_BF(2)
    gload_lds16(srcB[2], Bn + dB[2]);
    PHASE_MID()
    MFMA_GATE(2)
    PHASE_END("vmcnt(7)")   // retire B3(t)

    // phase 3 (gate 3): read bF3; issue B3(t+1)
    READ_BF(3)
    gload_lds16(srcB[3], Bn + dB[3]);
    PHASE_MID()
    MFMA_GATE(3)
    PHASE_END("vmcnt(3)")   // retire A(t+1)x4 + B0(t+1); keep B1-B3(t+1) in flight

#pragma unroll
    for (int i = 0; i < 4; ++i) srcA[i] += BK;
#pragma unroll
    for (int g = 0; g < 4; ++g) srcB[g] += BK;
  }

  // ---- last tile (no prefetch; drain remaining loads progressively) ----
  {
    const int p = (NKT - 1) & 1;
    const unsigned short* Ab = &lA[p][0];
    const unsigned short* Bb = &lB[p][0];

    bf16x8 aF[4][2];
    bf16x8 bF[2][2];

    READ_AF()
    READ_BF(0)
    PHASE_MID()
    MFMA_GATE(0)
    PHASE_END("vmcnt(2)")   // retire B1(last)

    READ_BF(1)
    PHASE_MID()
    MFMA_GATE(1)
    PHASE_END("vmcnt(1)")   // retire B2(last)

    READ_BF(2)
    PHASE_MID()
    MFMA_GATE(2)
    PHASE_END("vmcnt(0)")   // retire B3(last)

    READ_BF(3)
    PHASE_MID()
    MFMA_GATE(3)
    __builtin_amdgcn_s_setprio(0);
  }

  // ---- epilogue: gates + cell update, store h_new ----
  const int row0 = brow * 256 + wr * 64;
  const int col0 = bcol * 64 + wc * 32;
  float bv[4][2];
#pragma unroll
  for (int n = 0; n < 2; ++n) {
    int col = col0 + n * 16 + ll;
    bv[0][n] = bias_f[col];
    bv[1][n] = bias_i[col];
    bv[2][n] = bias_s[col];
    bv[3][n] = bias_p[col];
  }
#pragma unroll
  for (int m = 0; m < 4; ++m)
#pragma unroll
    for (int n = 0; n < 2; ++n)
#pragma unroll
      for (int j = 0; j < 4; ++j) {
        int row = row0 + m * 16 + lg * 4 + j;
        int col = col0 + n * 16 + ll;
        float zf = acc[0][m][n][j] + bv[0][n];
        float zi = acc[1][m][n][j] + bv[1][n];
        float zs = acc[2][m][n][j] + bv[2][n];
        float zp = acc[3][m][n][j] + bv[3][n];
        float fg = sigm(zf);
        float ig = sigm(zi);
        float sg = sigm(zs);
        float pg = tanh_fast(zp);
        float cn = c_in[(size_t)row * 1024 + col] * fg + ig * pg;
        out[(size_t)row * 1024 + col] = tanh_fast(cn) * sg;
      }
}

extern "C" void kernel_launch(void* const* d_in, const int* in_sizes, int n_in,
                              void* d_out, int out_size, void* d_ws, size_t ws_size,
                              hipStream_t stream) {
  const float* x  = (const float*)d_in[0];
  const float* h  = (const float*)d_in[1];
  const float* c  = (const float*)d_in[2];
  const float* Wf = (const float*)d_in[3];
  const float* bf = (const float*)d_in[4];
  const float* Wi = (const float*)d_in[5];
  const float* bi = (const float*)d_in[6];
  const float* Ws = (const float*)d_in[7];
  const float* bs = (const float*)d_in[8];
  const float* Wp = (const float*)d_in[9];
  const float* bp = (const float*)d_in[10];
  float* out = (float*)d_out;

  unsigned short* ws = (unsigned short*)d_ws;
  unsigned short* hx  = ws;                           // 4096*2048 bf16 = 16 MB
  unsigned short* wtb = ws + (size_t)4096 * 2048;     // 4*1024*2048 bf16 = 16 MB

  pack_hx_kernel<<<(BDIM * KDIM / 4) / 256, 256, 0, stream>>>(x, h, hx);

  dim3 tb(32, 8);
  dim3 tg(1024 / 32, 2048 / 32, 4);
  transpose_w4_kernel<<<tg, tb, 0, stream>>>(Wf, Wi, Ws, Wp, wtb);

  lstm_fused_kernel<<<256, 512, 0, stream>>>(hx, wtb, bf, bi, bs, bp, c, out);
}